// Round 6
// baseline (796.713 us; speedup 1.0000x reference)
//
#include <hip/hip_runtime.h>
#include <hip/hip_bf16.h>
#include <hip/hip_cooperative_groups.h>
#include <stdint.h>

namespace cg = cooperative_groups;

#define N_NODES 50000
#define N_EDGES 800000
#define FEAT 128
#define CAP 64          // packed bucket capacity per node
#define PSLOT 16        // slots per XCD-partition (lambda~3.2 -> P(ovf)~1e-8)
#define NCVT 1600000    // N*FEAT/4 half4 units

// pre2 block-swizzle geometry: edge blocks spread 5-per-16 among conv blocks.
#define B_CONV 6250     // NCVT/256
#define B_TRW  640      // 163840/256
#define B_TOT  10018    // 625*16 + 18

typedef __attribute__((ext_vector_type(4))) float floatx4;
typedef __attribute__((ext_vector_type(8))) _Float16 half8;
typedef __attribute__((ext_vector_type(4))) _Float16 half4;
typedef __attribute__((ext_vector_type(4))) unsigned short ushortx4;

__device__ __forceinline__ float bf2f(unsigned short u) {
  union { unsigned u; float f; } v; v.u = ((unsigned)u) << 16; return v.f;
}
__device__ __forceinline__ unsigned short f2bf(float f) {
  union { float f; unsigned u; } v; v.f = f;
  unsigned r = v.u + 0x7fffu + ((v.u >> 16) & 1u);
  return (unsigned short)(r >> 16);
}
__device__ __forceinline__ unsigned pack_edge(float w, int s) {
  _Float16 h = (_Float16)w;
  unsigned short hb = __builtin_bit_cast(unsigned short, h);
  return ((unsigned)s << 16) | (unsigned)hb;
}
__device__ __forceinline__ float edge_w(unsigned e) {
  unsigned short hb = (unsigned short)(e & 0xFFFFu);
  return (float)__builtin_bit_cast(_Float16, hb);
}
__device__ __forceinline__ int edge_src(unsigned e) { return (int)(e >> 16); }

// int8 shadow row dequant: 8 bytes -> 8 halves, val = sc*(q-128)
__device__ __forceinline__ half8 deq8(uint2 v, float sc) {
  half8 r;
  r[0] = (_Float16)(sc * (float)((int)(v.x & 0xFFu) - 128));
  r[1] = (_Float16)(sc * (float)((int)((v.x >> 8) & 0xFFu) - 128));
  r[2] = (_Float16)(sc * (float)((int)((v.x >> 16) & 0xFFu) - 128));
  r[3] = (_Float16)(sc * (float)((int)(v.x >> 24) - 128));
  r[4] = (_Float16)(sc * (float)((int)(v.y & 0xFFu) - 128));
  r[5] = (_Float16)(sc * (float)((int)((v.y >> 8) & 0xFFu) - 128));
  r[6] = (_Float16)(sc * (float)((int)((v.y >> 16) & 0xFFu) - 128));
  r[7] = (_Float16)(sc * (float)((int)(v.y >> 24) - 128));
  return r;
}

// ---- pre1 (single block, cheap): dtype detect + params->fp32 ----
__global__ void k_pre1(const unsigned short* __restrict__ x,
                       const void* b0, const void* b1, const void* b2,
                       const void* wl, const void* bl,
                       float* __restrict__ pf, int* __restrict__ flag) {
  __shared__ int cnt_s;
  __shared__ int fl_s;
  int tid = threadIdx.x;
  if (tid == 0) cnt_s = 0;
  __syncthreads();
  int big = 0;
  for (int i = tid; i < 4096; i += 256) {
    unsigned short u = x[2 * i];
    int e = (u >> 7) & 0xFF;
    if (e >= 0xE0) big++;
  }
  atomicAdd(&cnt_s, big);
  __syncthreads();
  if (tid == 0) { fl_s = (cnt_s > 16) ? 1 : 0; flag[0] = fl_s; }
  __syncthreads();
  int fl = fl_s;
  for (int i = tid; i < 513; i += 256) {
    const void* src; int off;
    if (i < 128)      { src = b0; off = i; }
    else if (i < 256) { src = b1; off = i - 128; }
    else if (i < 384) { src = b2; off = i - 256; }
    else if (i < 512) { src = wl; off = i - 384; }
    else              { src = bl; off = 0; }
    pf[i] = fl ? ((const float*)src)[off] : bf2f(((const unsigned short*)src)[off]);
  }
}

// ---- pre2 (fused, block-swizzled segments):
//   EDGE  deg[s]++; pos=cnt8[p][d]++; edata16[p][d][pos]=src with p=blockIdx&7.
//   CONV  x -> fp16 T0 + int8 shadow Q0/S0 — ALL conv traffic nontemporal so the
//         per-XCD L2 holds ONLY the ~1.9MB bucket/cnt slice (the R5 partition
//         layout made slices XCD-exclusive; nt removes the stream eviction that
//         defeated it).
//   TRW   transpose W0,W1 -> fp16 wt
//   PREV  v_k = W2_k @ Wl + const
__global__ void k_pre2(const void* __restrict__ xp,
                       const void* __restrict__ w0, const void* __restrict__ w1,
                       const void* __restrict__ w2,
                       const int* __restrict__ esrc, const int* __restrict__ edst,
                       _Float16* __restrict__ t0,
                       unsigned char* __restrict__ q0, float* __restrict__ s0,
                       _Float16* __restrict__ wt,
                       int* __restrict__ deg, int* __restrict__ cnt8,
                       unsigned short* __restrict__ edata16,
                       float* __restrict__ pf,
                       const int* __restrict__ flag) {
  int b = blockIdx.x, tid = threadIdx.x;
  int o;
  if (b < 10000) {
    int g = b >> 4, r = b & 15;
    if (r < 5) {
      // EDGE block; partition index = dispatch-id mod 8 ~= XCD id
      int p = b & 7;
      int e = (g * 5 + r) * 256 + tid;
      int s = __builtin_nontemporal_load(esrc + e);
      int d = __builtin_nontemporal_load(edst + e);
      if (s == d) return;
      atomicAdd(&deg[s], 1);
      int pos = atomicAdd(&cnt8[p * N_NODES + d], 1);
      if (pos < PSLOT)
        edata16[(size_t)p * (N_NODES * PSLOT) + d * PSLOT + pos] = (unsigned short)s;
      return;
    }
    o = g * 11 + (r - 5);
  } else {
    o = 6875 + (b - 10000);
  }
  if (o < B_CONV) {
    int i = o * 256 + tid;
    int fl = flag[0];
    floatx4 v;
    if (fl) {
      v = __builtin_nontemporal_load((const floatx4*)xp + i);
    } else {
      ushortx4 u = __builtin_nontemporal_load((const ushortx4*)xp + i);
      v.x = bf2f(u.x); v.y = bf2f(u.y); v.z = bf2f(u.z); v.w = bf2f(u.w);
    }
    half4 h;
    h[0] = (_Float16)v.x; h[1] = (_Float16)v.y; h[2] = (_Float16)v.z; h[3] = (_Float16)v.w;
    __builtin_nontemporal_store(h, (half4*)t0 + i);
    float mx = fmaxf(fmaxf(fabsf(v.x), fabsf(v.y)), fmaxf(fabsf(v.z), fabsf(v.w)));
#pragma unroll
    for (int d = 1; d < 32; d <<= 1) mx = fmaxf(mx, __shfl_xor(mx, d));
    float inv = mx > 0.f ? 127.f / mx : 0.f;
    int qa = (int)rintf(v.x * inv) + 128;
    int qb = (int)rintf(v.y * inv) + 128;
    int qc = (int)rintf(v.z * inv) + 128;
    int qd = (int)rintf(v.w * inv) + 128;
    unsigned pk = (unsigned)qa | ((unsigned)qb << 8) | ((unsigned)qc << 16) | ((unsigned)qd << 24);
    __builtin_nontemporal_store(pk, (unsigned*)q0 + i);
    if ((i & 31) == 0) __builtin_nontemporal_store(mx > 0.f ? mx / 127.f : 0.f, s0 + (i >> 5));
  } else if (o < B_CONV + B_TRW) {
    int t = (o - B_CONV) * 256 + tid;
    int fl = flag[0];
    int li = t >> 14;           // 0..9
    int r = t & 16383;
    int n = r >> 7, kk = r & 127;
    int l = li / 5, k = li - l * 5;
    const void* w = (l == 0) ? w0 : w1;
    int idx = k * 16384 + kk * 128 + n;
    float v = fl ? ((const float*)w)[idx] : bf2f(((const unsigned short*)w)[idx]);
    wt[t] = (_Float16)v;
  } else {
    int t = (o - B_CONV - B_TRW) * 256 + tid;
    if (t > 640) return;
    int fl = flag[0];
    if (t < 640) {
      int k = t >> 7, f = t & 127;
      float s = 0.f;
      const int base = (k << 14) + (f << 7);
      if (fl) {
        const float* w = (const float*)w2 + base;
#pragma unroll 8
        for (int q = 0; q < 128; ++q) s += w[q] * pf[384 + q];
      } else {
        const unsigned short* w = (const unsigned short*)w2 + base;
#pragma unroll 8
        for (int q = 0; q < 128; ++q) s += bf2f(w[q]) * pf[384 + q];
      }
      pf[520 + t] = s;
    } else {
      float s = 0.f;
      for (int q = 0; q < 128; ++q) s += pf[256 + q] * pf[384 + q];
      pf[1160] = s + pf[512];
    }
  }
}

// ---- k_wpack: compact 8 partitions/node + final deg -> packed 4B edata + cnt. ----
__global__ __launch_bounds__(256) void k_wpack(const unsigned short* __restrict__ ed16,
                                               const int* __restrict__ cnt8,
                                               const int* __restrict__ deg,
                                               int* __restrict__ cnt,
                                               unsigned* __restrict__ edata) {
  int node = (blockIdx.x * 256 + threadIdx.x) >> 6;
  int lane = threadIdx.x & 63;
  if (node >= N_NODES) return;
  int c[8], off[8], tot = 0;
#pragma unroll
  for (int p = 0; p < 8; ++p) {
    int v = cnt8[p * N_NODES + node];
    if (v > PSLOT) v = PSLOT;
    c[p] = v; off[p] = tot; tot += v;
  }
  if (lane == 0) cnt[node] = tot > CAP ? CAP : tot;
  int dd = deg[node];
  float rd = dd > 0 ? rsqrtf((float)dd) : 0.f;
#pragma unroll
  for (int it = 0; it < 2; ++it) {
    int p = (lane >> 4) + it * 4;
    int s = lane & 15;
    if (s < c[p]) {
      int pos = off[p] + s;
      if (pos < CAP) {
        int sr = (int)ed16[(size_t)p * (N_NODES * PSLOT) + node * PSLOT + s];
        int ds = deg[sr];
        float w = (ds > 0 && dd > 0) ? -rsqrtf((float)ds) * rd : 0.f;
        edata[(node << 6) + pos] = pack_edge(w, sr);
      }
    }
  }
}

// ---- feature SpMV (unchanged from R5) ----
__global__ __launch_bounds__(256) void k_spmv(const unsigned* __restrict__ edata,
                                              const int* __restrict__ cnt,
                                              const unsigned char* __restrict__ Q,
                                              const float* __restrict__ S,
                                              const _Float16* __restrict__ Z,
                                              _Float16* __restrict__ Y,
                                              unsigned char* __restrict__ Qo,
                                              float* __restrict__ So,
                                              float alpha, int hasZ, int writeY) {
  int wave = threadIdx.x >> 6, lane = threadIdx.x & 63;
  int q = lane >> 4, l16 = lane & 15;
  int node = blockIdx.x * 16 + wave * 4 + q;
  if (node >= N_NODES) return;
  int n_e = cnt[node]; if (n_e > CAP) n_e = CAP;
  int base = node << 6;

  float acc[8];
#pragma unroll
  for (int f = 0; f < 8; ++f) acc[f] = 0.f;
  float wsum = 0.f;

  unsigned e0 = (0 < n_e) ? edata[base + 0] : 0u;
  unsigned e1 = (1 < n_e) ? edata[base + 1] : 0u;
  unsigned e2 = (2 < n_e) ? edata[base + 2] : 0u;
  unsigned e3 = (3 < n_e) ? edata[base + 3] : 0u;
  unsigned e4 = (4 < n_e) ? edata[base + 4] : 0u;
  unsigned e5 = (5 < n_e) ? edata[base + 5] : 0u;
  unsigned e6 = (6 < n_e) ? edata[base + 6] : 0u;
  unsigned e7 = (7 < n_e) ? edata[base + 7] : 0u;
  uint2 r0 = ((const uint2*)(Q + (size_t)edge_src(e0) * FEAT))[l16];
  uint2 r1 = ((const uint2*)(Q + (size_t)edge_src(e1) * FEAT))[l16];
  uint2 r2 = ((const uint2*)(Q + (size_t)edge_src(e2) * FEAT))[l16];
  uint2 r3 = ((const uint2*)(Q + (size_t)edge_src(e3) * FEAT))[l16];
  float s0 = S[edge_src(e0)], s1 = S[edge_src(e1)], s2 = S[edge_src(e2)], s3 = S[edge_src(e3)];

  for (int j = 0; j < n_e; j += 4) {
    float ws0 = edge_w(e0) * s0, ws1 = edge_w(e1) * s1;
    float ws2 = edge_w(e2) * s2, ws3 = edge_w(e3) * s3;
    uint2 c0 = r0, c1 = r1, c2 = r2, c3 = r3;
    e0 = e4; e1 = e5; e2 = e6; e3 = e7;
    e4 = (j + 8 < n_e) ? edata[base + j + 8] : 0u;
    e5 = (j + 9 < n_e) ? edata[base + j + 9] : 0u;
    e6 = (j + 10 < n_e) ? edata[base + j + 10] : 0u;
    e7 = (j + 11 < n_e) ? edata[base + j + 11] : 0u;
    r0 = ((const uint2*)(Q + (size_t)edge_src(e0) * FEAT))[l16];
    r1 = ((const uint2*)(Q + (size_t)edge_src(e1) * FEAT))[l16];
    r2 = ((const uint2*)(Q + (size_t)edge_src(e2) * FEAT))[l16];
    r3 = ((const uint2*)(Q + (size_t)edge_src(e3) * FEAT))[l16];
    s0 = S[edge_src(e0)]; s1 = S[edge_src(e1)]; s2 = S[edge_src(e2)]; s3 = S[edge_src(e3)];
#define DEC8(c, w)                                                        \
    acc[0] = fmaf(w, (float)(c.x & 0xFFu), acc[0]);                       \
    acc[1] = fmaf(w, (float)((c.x >> 8) & 0xFFu), acc[1]);                \
    acc[2] = fmaf(w, (float)((c.x >> 16) & 0xFFu), acc[2]);               \
    acc[3] = fmaf(w, (float)(c.x >> 24), acc[3]);                         \
    acc[4] = fmaf(w, (float)(c.y & 0xFFu), acc[4]);                       \
    acc[5] = fmaf(w, (float)((c.y >> 8) & 0xFFu), acc[5]);                \
    acc[6] = fmaf(w, (float)((c.y >> 16) & 0xFFu), acc[6]);               \
    acc[7] = fmaf(w, (float)(c.y >> 24), acc[7]);
    DEC8(c0, ws0) DEC8(c1, ws1) DEC8(c2, ws2) DEC8(c3, ws3)
#undef DEC8
    wsum += (ws0 + ws1) + (ws2 + ws3);
  }
  float rx[8];
  float b128 = 128.f * wsum;
  if (hasZ) {
    half8 z = ((const half8*)(Z + (size_t)node * FEAT))[l16];
#pragma unroll
    for (int f = 0; f < 8; ++f) rx[f] = fmaf(alpha, acc[f] - b128, -(float)z[f]);
  } else {
#pragma unroll
    for (int f = 0; f < 8; ++f) rx[f] = alpha * (acc[f] - b128);
  }
  if (writeY) {
    half8 res;
#pragma unroll
    for (int f = 0; f < 8; ++f) res[f] = (_Float16)rx[f];
    ((half8*)(Y + (size_t)node * FEAT))[l16] = res;
  }
  float mx = 0.f;
#pragma unroll
  for (int f = 0; f < 8; ++f) mx = fmaxf(mx, fabsf(rx[f]));
#pragma unroll
  for (int o = 1; o < 16; o <<= 1) mx = fmaxf(mx, __shfl_xor(mx, o));
  float inv = mx > 0.f ? 127.f / mx : 0.f;
  int qb[8];
#pragma unroll
  for (int f = 0; f < 8; ++f) qb[f] = (int)rintf(rx[f] * inv) + 128;
  uint2 p;
  p.x = (unsigned)qb[0] | ((unsigned)qb[1] << 8) | ((unsigned)qb[2] << 16) | ((unsigned)qb[3] << 24);
  p.y = (unsigned)qb[4] | ((unsigned)qb[5] << 8) | ((unsigned)qb[6] << 16) | ((unsigned)qb[7] << 24);
  ((uint2*)(Qo + (size_t)node * FEAT))[l16] = p;
  if (l16 == 0) So[node] = mx > 0.f ? mx / 127.f : 0.f;
}

// ---- k_clen: all 4 Clenshaw scalar-SpMV steps in ONE cooperative kernel.
// Math bit-identical to the former k_smv chain; grid.sync() between steps
// replaces 3 full launch+drain cycles. 1024 blocks co-resident (no LDS, low
// VGPR, 256 thr -> well under 8 blocks/CU cap).
__global__ __launch_bounds__(256) void k_clen(const unsigned* __restrict__ edata,
                                              const int* __restrict__ cnt,
                                              const float* __restrict__ hb,  // h0..h4 (5N)
                                              float* __restrict__ bb,        // b3,b2,b1 (3N)
                                              void* __restrict__ outp,
                                              const int* __restrict__ flag,
                                              const float* __restrict__ cptr) {
  cg::grid_group grid = cg::this_grid();
  int wave = threadIdx.x >> 6, lane = threadIdx.x & 63;
  int q = lane >> 4, l16 = lane & 15;
  const float* h0 = hb;
  const float* h1 = hb + N_NODES;
  const float* h2 = hb + 2 * N_NODES;
  const float* h3 = hb + 3 * N_NODES;
  const float* h4 = hb + 4 * N_NODES;
  float* b3 = bb;
  float* b2 = bb + N_NODES;
  float* b1 = bb + 2 * N_NODES;
  const float* hs[4] = {h3, h2, h1, h0};
  const float* bs[4] = {h4, b3, b2, b1};
  const float* ps[4] = {nullptr, h4, b3, b2};
  float* ys[4] = {b3, b2, b1, nullptr};
#pragma unroll
  for (int st = 0; st < 4; ++st) {
    float cL = (st == 3) ? 1.f : 2.f;
    const float* bsrc = bs[st];
    const float* hsrc = hs[st];
    const float* psrc = ps[st];
    float* ydst = ys[st];
    for (int nb = blockIdx.x * 16; nb < N_NODES; nb += gridDim.x * 16) {
      int node = nb + wave * 4 + q;
      if (node < N_NODES) {
        int n_e = cnt[node]; if (n_e > CAP) n_e = CAP;
        int base = node << 6;
        float s = 0.f;
        for (int j = l16; j < n_e; j += 16) {
          unsigned e = edata[base + j];
          s = fmaf(edge_w(e), bsrc[edge_src(e)], s);
        }
#pragma unroll
        for (int o = 1; o < 16; o <<= 1) s += __shfl_xor(s, o);
        if (l16 == 0) {
          float r = fmaf(cL, s, hsrc[node]) - (psrc ? psrc[node] : 0.f);
          if (st < 3) {
            ydst[node] = r;
          } else {
            r += cptr[0];
            if (flag[0]) ((float*)outp)[node] = r;
            else ((unsigned short*)outp)[node] = f2bf(r);
          }
        }
      }
    }
    if (st < 3) grid.sync();
  }
}

// ---- fused layer GEMM (unchanged from R5) ----
__global__ __launch_bounds__(256) void k_gemm(const unsigned char* __restrict__ qa0, const unsigned char* __restrict__ qa1,
                                              const unsigned char* __restrict__ qa2, const unsigned char* __restrict__ qa3,
                                              const unsigned char* __restrict__ qa4,
                                              const float* __restrict__ sa0, const float* __restrict__ sa1,
                                              const float* __restrict__ sa2, const float* __restrict__ sa3,
                                              const float* __restrict__ sa4,
                                              const _Float16* __restrict__ wt,  // [5][128(n)][128(k)] fp16
                                              const float* __restrict__ bias,
                                              _Float16* __restrict__ dst, int mode,
                                              const float* __restrict__ v0,   // 5x128
                                              float* __restrict__ hout,       // 5xN
                                              unsigned char* __restrict__ q8out,
                                              float* __restrict__ scout) {
  __shared__ _Float16 lb[128 * 136];
  const unsigned char* qp[5] = {qa0, qa1, qa2, qa3, qa4};
  const float* sp[5] = {sa0, sa1, sa2, sa3, sa4};
  int tid = threadIdx.x, wave = tid >> 6, lane = tid & 63;
  int quad = lane >> 4, l16 = lane & 15;
  int m0 = blockIdx.x * 128;
  floatx4 acc[2][8];
#pragma unroll
  for (int s = 0; s < 2; ++s)
#pragma unroll
    for (int j = 0; j < 8; ++j) acc[s][j] = (floatx4){0.f, 0.f, 0.f, 0.f};
  int arow[2];
  bool aval[2];
#pragma unroll
  for (int s = 0; s < 2; ++s) {
    arow[s] = m0 + wave * 32 + s * 16 + l16;
    aval[s] = arow[s] < N_NODES;
  }

#pragma unroll
  for (int k = 0; k < 5; ++k) {
    __syncthreads();
    {
      int n = tid >> 1, half = tid & 1;
      const uint4* spw = (const uint4*)(wt + k * 16384 + n * 128 + half * 64);
      uint4* dq = (uint4*)(lb + n * 136 + half * 64);
#pragma unroll
      for (int i = 0; i < 8; ++i) dq[i] = spw[i];
    }
    __syncthreads();
    const unsigned char* Aq = qp[k];
    float sk[2];
#pragma unroll
    for (int s = 0; s < 2; ++s) sk[s] = aval[s] ? sp[k][arow[s]] : 0.f;
#pragma unroll
    for (int ki = 0; ki < 4; ++ki) {
      half8 af[2];
#pragma unroll
      for (int s = 0; s < 2; ++s) {
        uint2 qv = aval[s]
          ? *((const uint2*)(Aq + (size_t)arow[s] * FEAT + ki * 32 + quad * 8))
          : make_uint2(0x80808080u, 0x80808080u);
        af[s] = deq8(qv, sk[s]);
      }
#pragma unroll
      for (int j = 0; j < 8; ++j) {
        half8 bf = *((const half8*)(lb + (j * 16 + l16) * 136 + ki * 32 + quad * 8));
        acc[0][j] = __builtin_amdgcn_mfma_f32_16x16x32_f16(af[0], bf, acc[0][j], 0, 0, 0);
        acc[1][j] = __builtin_amdgcn_mfma_f32_16x16x32_f16(af[1], bf, acc[1][j], 0, 0, 0);
      }
    }
  }
#pragma unroll
  for (int s = 0; s < 2; ++s) {
    int rbase = m0 + wave * 32 + s * 16 + quad * 4;
    if (mode == 0) {
      float mx[4] = {0.f, 0.f, 0.f, 0.f};
#pragma unroll
      for (int j = 0; j < 8; ++j) {
        int col = j * 16 + l16;
        float b = bias[col];
#pragma unroll
        for (int r = 0; r < 4; ++r) {
          int m = rbase + r;
          float v = fmaxf(acc[s][j][r] + b, 0.f);
          if (m < N_NODES) dst[(size_t)m * FEAT + col] = (_Float16)v;
          mx[r] = fmaxf(mx[r], v);
        }
      }
#pragma unroll
      for (int o = 1; o < 16; o <<= 1) {
#pragma unroll
        for (int r = 0; r < 4; ++r) mx[r] = fmaxf(mx[r], __shfl_xor(mx[r], o));
      }
      float inv[4];
#pragma unroll
      for (int r = 0; r < 4; ++r) inv[r] = mx[r] > 0.f ? 127.f / mx[r] : 0.f;
      if (l16 == 0) {
#pragma unroll
        for (int r = 0; r < 4; ++r) {
          int m = rbase + r;
          if (m < N_NODES) scout[m] = mx[r] > 0.f ? mx[r] / 127.f : 0.f;
        }
      }
#pragma unroll
      for (int j = 0; j < 8; ++j) {
        int col = j * 16 + l16;
        float b = bias[col];
#pragma unroll
        for (int r = 0; r < 4; ++r) {
          int m = rbase + r;
          if (m < N_NODES) {
            float v = fmaxf(acc[s][j][r] + b, 0.f);
            int qv = (int)rintf(v * inv[r]) + 128;
            q8out[(size_t)m * FEAT + col] = (unsigned char)qv;
          }
        }
      }
    } else {
      float p[5][4];
#pragma unroll
      for (int k = 0; k < 5; ++k)
#pragma unroll
        for (int r = 0; r < 4; ++r) p[k][r] = 0.f;
#pragma unroll
      for (int j = 0; j < 8; ++j) {
        int col = j * 16 + l16;
        float b = bias[col];
        float vv[5];
#pragma unroll
        for (int k = 0; k < 5; ++k) vv[k] = v0[k * 128 + col];
#pragma unroll
        for (int r = 0; r < 4; ++r) {
          float val = fmaxf(acc[s][j][r] + b, 0.f);
#pragma unroll
          for (int k = 0; k < 5; ++k) p[k][r] = fmaf(val, vv[k], p[k][r]);
        }
      }
#pragma unroll
      for (int o = 1; o < 16; o <<= 1) {
#pragma unroll
        for (int k = 0; k < 5; ++k)
#pragma unroll
          for (int r = 0; r < 4; ++r) p[k][r] += __shfl_xor(p[k][r], o);
      }
      if (l16 == 0) {
#pragma unroll
        for (int r = 0; r < 4; ++r) {
          int m = rbase + r;
          if (m < N_NODES) {
#pragma unroll
            for (int k = 0; k < 5; ++k) hout[k * N_NODES + m] = p[k][r];
          }
        }
      }
    }
  }
}

extern "C" void kernel_launch(void* const* d_in, const int* in_sizes, int n_in,
                              void* d_out, int out_size, void* d_ws, size_t ws_size,
                              hipStream_t stream) {
  const void* x  = d_in[0];
  const int* ei  = (const int*)d_in[1];
  const void* w0 = d_in[2];
  const void* b0 = d_in[3];
  const void* w1 = d_in[4];
  const void* b1 = d_in[5];
  const void* w2 = d_in[6];
  const void* b2 = d_in[7];
  const void* wl = d_in[8];
  const void* bl = d_in[9];
  const int* src = ei;
  const int* dst = ei + N_EDGES;

  char* ws = (char*)d_ws;
  size_t off = 0;
  auto alloc = [&](size_t bytes) -> char* {
    char* p = ws + off;
    off += (bytes + 255) & ~(size_t)255;
    return p;
  };
  _Float16* T[3];
  for (int i = 0; i < 3; ++i) T[i] = (_Float16*)alloc(sizeof(_Float16) * N_NODES * FEAT);  // fp16 masters (Z-sources only)
  unsigned char* Q[5];
  for (int i = 0; i < 5; ++i) Q[i] = (unsigned char*)alloc((size_t)N_NODES * FEAT);        // int8 shadows
  float* S[5];
  for (int i = 0; i < 5; ++i) S[i] = (float*)alloc(sizeof(float) * N_NODES);               // row scales
  unsigned* edata = (unsigned*)alloc(sizeof(unsigned) * N_NODES * CAP);                    // 12.8 MB packed
  unsigned short* edata16 = (unsigned short*)alloc(sizeof(unsigned short) * 8 * N_NODES * PSLOT); // 12.8 MB partitioned
  int* cnt8 = (int*)alloc(sizeof(int) * N_NODES * 9);  // cnt8[8][N] + deg[N] (one memset)
  int* deg = cnt8 + 8 * N_NODES;
  int* cnt = (int*)alloc(sizeof(int) * N_NODES);       // written by wpack, no memset
  _Float16* wt = (_Float16*)alloc(sizeof(_Float16) * 163840);
  float* pf = (float*)alloc(sizeof(float) * 1536);
  float* hbuf = (float*)alloc(sizeof(float) * 5 * N_NODES);  // h_k = relu(H1).v_k
  float* bbuf = (float*)alloc(sizeof(float) * 3 * N_NODES);  // Clenshaw b3,b2,b1
  int* flag = (int*)alloc(sizeof(int));

  hipMemsetAsync(cnt8, 0, sizeof(int) * N_NODES * 9, stream);
  k_pre1<<<1, 256, 0, stream>>>((const unsigned short*)x, b0, b1, b2, wl, bl, pf, flag);
  k_pre2<<<B_TOT, 256, 0, stream>>>(x, w0, w1, w2, src, dst, T[0], Q[0], S[0], wt,
                                    deg, cnt8, edata16, pf, flag);
  k_wpack<<<(N_NODES * 64 + 255) / 256, 256, 0, stream>>>(edata16, cnt8, deg, cnt, edata);

  int nblk_spmv = (N_NODES + 15) / 16;
  int nblk_gemm = (N_NODES + 127) / 128;
  const float* v = pf + 520;       // v_k, 5x128
  const float* cc = pf + 1160;     // b2.Wl + bl

  // layers 0,1: T-chain via int8-shadow gathers; fp16 masters only for Z-operands.
  for (int l = 0; l < 2; ++l) {
    k_spmv<<<nblk_spmv, 256, 0, stream>>>(edata, cnt, Q[0], S[0], nullptr, T[1], Q[1], S[1], 1.f, 0, 1);
    k_spmv<<<nblk_spmv, 256, 0, stream>>>(edata, cnt, Q[1], S[1], T[0], T[2], Q[2], S[2], 2.f, 1, 1);
    k_spmv<<<nblk_spmv, 256, 0, stream>>>(edata, cnt, Q[2], S[2], T[1], nullptr, Q[3], S[3], 2.f, 1, 0);
    k_spmv<<<nblk_spmv, 256, 0, stream>>>(edata, cnt, Q[3], S[3], T[2], nullptr, Q[4], S[4], 2.f, 1, 0);
    k_gemm<<<nblk_gemm, 256, 0, stream>>>(Q[0], Q[1], Q[2], Q[3], Q[4],
                                          S[0], S[1], S[2], S[3], S[4],
                                          wt + l * 5 * 16384, pf + l * 128, T[0],
                                          l, v, hbuf, Q[0], S[0]);
  }
  // layer 2: all 4 Clenshaw steps in one cooperative launch
  {
    void* outp = d_out;
    const unsigned* edc = edata;
    const int* cntc = cnt;
    const float* hbc = hbuf;
    float* bbc = bbuf;
    const int* flc = flag;
    const float* ccc = cc;
    void* args[] = {(void*)&edc, (void*)&cntc, (void*)&hbc, (void*)&bbc,
                    (void*)&outp, (void*)&flc, (void*)&ccc};
    hipLaunchCooperativeKernel((const void*)k_clen, dim3(1024), dim3(256), args, 0, stream);
  }
}

// Round 7
// 454.248 us; speedup vs baseline: 1.7539x; 1.7539x over previous
//
#include <hip/hip_runtime.h>
#include <hip/hip_bf16.h>
#include <stdint.h>

#define N_NODES 50000
#define N_EDGES 800000
#define FEAT 128
#define CAP 64          // packed bucket capacity per node
#define PSLOT 16        // slots per XCD-partition (lambda~2/partition)
#define NCVT 1600000    // N*FEAT/4 half4 units

// pre2 geometry, 4 items/thread (MLP-4): 1024 units per block.
// [0,2346): triplets {conv,conv,edge}; [2346,2506): TRW; [2506,2509): PREV.
#define B_CONV_N 1563   // ceil(NCVT/1024)
#define B_EDGE_N 782    // ceil(N_EDGES/1024)
#define B_TOT 2509

typedef __attribute__((ext_vector_type(4))) float floatx4;
typedef __attribute__((ext_vector_type(8))) _Float16 half8;
typedef __attribute__((ext_vector_type(4))) _Float16 half4;
typedef __attribute__((ext_vector_type(4))) unsigned short ushortx4;
typedef __attribute__((ext_vector_type(4))) int intx4;

__device__ __forceinline__ float bf2f(unsigned short u) {
  union { unsigned u; float f; } v; v.u = ((unsigned)u) << 16; return v.f;
}
__device__ __forceinline__ unsigned short f2bf(float f) {
  union { float f; unsigned u; } v; v.f = f;
  unsigned r = v.u + 0x7fffu + ((v.u >> 16) & 1u);
  return (unsigned short)(r >> 16);
}
__device__ __forceinline__ unsigned pack_edge(float w, int s) {
  _Float16 h = (_Float16)w;
  unsigned short hb = __builtin_bit_cast(unsigned short, h);
  return ((unsigned)s << 16) | (unsigned)hb;
}
__device__ __forceinline__ float edge_w(unsigned e) {
  unsigned short hb = (unsigned short)(e & 0xFFFFu);
  return (float)__builtin_bit_cast(_Float16, hb);
}
__device__ __forceinline__ int edge_src(unsigned e) { return (int)(e >> 16); }

// int8 shadow row dequant: 8 bytes -> 8 halves, val = sc*(q-128)
__device__ __forceinline__ half8 deq8(uint2 v, float sc) {
  half8 r;
  r[0] = (_Float16)(sc * (float)((int)(v.x & 0xFFu) - 128));
  r[1] = (_Float16)(sc * (float)((int)((v.x >> 8) & 0xFFu) - 128));
  r[2] = (_Float16)(sc * (float)((int)((v.x >> 16) & 0xFFu) - 128));
  r[3] = (_Float16)(sc * (float)((int)(v.x >> 24) - 128));
  r[4] = (_Float16)(sc * (float)((int)(v.y & 0xFFu) - 128));
  r[5] = (_Float16)(sc * (float)((int)((v.y >> 8) & 0xFFu) - 128));
  r[6] = (_Float16)(sc * (float)((int)((v.y >> 16) & 0xFFu) - 128));
  r[7] = (_Float16)(sc * (float)((int)(v.y >> 24) - 128));
  return r;
}

// ---- pre1 (64 blocks): all blocks zero cnt8/deg (replaces memset launch);
// block 0 additionally: dtype detect + params->fp32.
__global__ void k_pre1(const unsigned short* __restrict__ x,
                       const void* b0, const void* b1, const void* b2,
                       const void* wl, const void* bl,
                       float* __restrict__ pf, int* __restrict__ flag,
                       int* __restrict__ cnt8) {
  int tid = threadIdx.x;
  intx4 z = {0, 0, 0, 0};
  for (int i = blockIdx.x * 256 + tid; i < 112500; i += 64 * 256)  // 9*N ints /4
    ((intx4*)cnt8)[i] = z;
  if (blockIdx.x != 0) return;
  __shared__ int cnt_s;
  __shared__ int fl_s;
  if (tid == 0) cnt_s = 0;
  __syncthreads();
  int big = 0;
  for (int i = tid; i < 4096; i += 256) {
    unsigned short u = x[2 * i];
    int e = (u >> 7) & 0xFF;
    if (e >= 0xE0) big++;
  }
  atomicAdd(&cnt_s, big);
  __syncthreads();
  if (tid == 0) { fl_s = (cnt_s > 16) ? 1 : 0; flag[0] = fl_s; }
  __syncthreads();
  int fl = fl_s;
  for (int i = tid; i < 513; i += 256) {
    const void* src; int off;
    if (i < 128)      { src = b0; off = i; }
    else if (i < 256) { src = b1; off = i - 128; }
    else if (i < 384) { src = b2; off = i - 256; }
    else if (i < 512) { src = wl; off = i - 384; }
    else              { src = bl; off = 0; }
    pf[i] = fl ? ((const float*)src)[off] : bf2f(((const unsigned short*)src)[off]);
  }
}

// ---- pre2 (fused; every segment 4 items/thread for MLP — the R0-R6 versions
// were 1 item/thread = 1 load in flight = latency-starved at 1.2-1.4 TB/s):
//   CONV  x -> fp16 T0 + int8 shadow Q0/S0 (4 independent 16B loads issued first)
//   EDGE  4 edges via one int4 pair: deg[s]++; cnt8[p][d]++; edata16[p][d][pos]=src
//   TRW   transpose W0,W1 -> fp16 wt
//   PREV  v_k = W2_k @ Wl + const
__global__ void k_pre2(const void* __restrict__ xp,
                       const void* __restrict__ w0, const void* __restrict__ w1,
                       const void* __restrict__ w2,
                       const int* __restrict__ esrc, const int* __restrict__ edst,
                       _Float16* __restrict__ t0,
                       unsigned char* __restrict__ q0, float* __restrict__ s0,
                       _Float16* __restrict__ wt,
                       int* __restrict__ deg, int* __restrict__ cnt8,
                       unsigned short* __restrict__ edata16,
                       float* __restrict__ pf,
                       const int* __restrict__ flag) {
  int b = blockIdx.x, tid = threadIdx.x;
  if (b < 2346) {
    int g = b / 3, r = b - g * 3;
    if (r == 2) {
      // EDGE block: 1024 edges, 4 consecutive per thread (one intx4 pair)
      int p = b & 7;  // partition ~ XCD (round-robin dispatch)
      int e0 = (g * 256 + tid) * 4;
      if (e0 >= N_EDGES) return;
      intx4 ss = __builtin_nontemporal_load((const intx4*)(esrc + e0));
      intx4 dd = __builtin_nontemporal_load((const intx4*)(edst + e0));
#pragma unroll
      for (int i = 0; i < 4; ++i) {
        int e = e0 + i;
        if (e >= N_EDGES) break;
        int s = ss[i], d = dd[i];
        if (s == d) continue;
        atomicAdd(&deg[s], 1);
        int pos = atomicAdd(&cnt8[p * N_NODES + d], 1);
        if (pos < PSLOT)
          edata16[(size_t)p * (N_NODES * PSLOT) + d * PSLOT + pos] = (unsigned short)s;
      }
      return;
    }
    int c = g * 2 + r;               // conv block id, [0, 1564); 1563 used
    if (c >= B_CONV_N) return;
    int fl = flag[0];
    int base = c * 1024 + tid;       // + 256*k, k=0..3; 32-lane rows preserved
    floatx4 v[4];
    bool ok[4];
#pragma unroll
    for (int k = 0; k < 4; ++k) {
      int i = base + k * 256;
      ok[k] = i < NCVT;
      if (ok[k]) {
        if (fl) {
          v[k] = __builtin_nontemporal_load((const floatx4*)xp + i);
        } else {
          ushortx4 u = __builtin_nontemporal_load((const ushortx4*)xp + i);
          v[k].x = bf2f(u.x); v[k].y = bf2f(u.y); v[k].z = bf2f(u.z); v[k].w = bf2f(u.w);
        }
      }
    }
#pragma unroll
    for (int k = 0; k < 4; ++k) {
      if (!ok[k]) continue;
      int i = base + k * 256;
      half4 h;
      h[0] = (_Float16)v[k].x; h[1] = (_Float16)v[k].y;
      h[2] = (_Float16)v[k].z; h[3] = (_Float16)v[k].w;
      ((half4*)t0)[i] = h;
      float mx = fmaxf(fmaxf(fabsf(v[k].x), fabsf(v[k].y)), fmaxf(fabsf(v[k].z), fabsf(v[k].w)));
#pragma unroll
      for (int d = 1; d < 32; d <<= 1) mx = fmaxf(mx, __shfl_xor(mx, d));
      float inv = mx > 0.f ? 127.f / mx : 0.f;
      int qa = (int)rintf(v[k].x * inv) + 128;
      int qb = (int)rintf(v[k].y * inv) + 128;
      int qc = (int)rintf(v[k].z * inv) + 128;
      int qd = (int)rintf(v[k].w * inv) + 128;
      ((unsigned*)q0)[i] = (unsigned)qa | ((unsigned)qb << 8) | ((unsigned)qc << 16) | ((unsigned)qd << 24);
      if ((i & 31) == 0) s0[i >> 5] = mx > 0.f ? mx / 127.f : 0.f;
    }
  } else if (b < 2506) {
    int tb = (b - 2346) * 1024 + tid;  // TRW: 160 blocks x 1024 = 163840 exact
    int fl = flag[0];
#pragma unroll
    for (int k = 0; k < 4; ++k) {
      int t = tb + k * 256;
      int li = t >> 14;           // 0..9
      int rr = t & 16383;
      int n = rr >> 7, kk = rr & 127;
      int l = li / 5, kq = li - l * 5;
      const void* w = (l == 0) ? w0 : w1;
      int idx = kq * 16384 + kk * 128 + n;
      float vv = fl ? ((const float*)w)[idx] : bf2f(((const unsigned short*)w)[idx]);
      wt[t] = (_Float16)vv;
    }
  } else {
    int t = (b - 2506) * 256 + tid;
    if (t > 640) return;
    int fl = flag[0];
    if (t < 640) {
      int k = t >> 7, f = t & 127;
      float s = 0.f;
      const int base = (k << 14) + (f << 7);
      if (fl) {
        const float* w = (const float*)w2 + base;
#pragma unroll 8
        for (int q = 0; q < 128; ++q) s += w[q] * pf[384 + q];
      } else {
        const unsigned short* w = (const unsigned short*)w2 + base;
#pragma unroll 8
        for (int q = 0; q < 128; ++q) s += bf2f(w[q]) * pf[384 + q];
      }
      pf[520 + t] = s;
    } else {
      float s = 0.f;
      for (int q = 0; q < 128; ++q) s += pf[256 + q] * pf[384 + q];
      pf[1160] = s + pf[512];
    }
  }
}

// ---- k_wpack: compact 8 partitions/node + final deg -> packed 4B edata + cnt. ----
__global__ __launch_bounds__(256) void k_wpack(const unsigned short* __restrict__ ed16,
                                               const int* __restrict__ cnt8,
                                               const int* __restrict__ deg,
                                               int* __restrict__ cnt,
                                               unsigned* __restrict__ edata) {
  int node = (blockIdx.x * 256 + threadIdx.x) >> 6;
  int lane = threadIdx.x & 63;
  if (node >= N_NODES) return;
  int c[8], off[8], tot = 0;
#pragma unroll
  for (int p = 0; p < 8; ++p) {
    int v = cnt8[p * N_NODES + node];
    if (v > PSLOT) v = PSLOT;
    c[p] = v; off[p] = tot; tot += v;
  }
  if (lane == 0) cnt[node] = tot > CAP ? CAP : tot;
  int dd = deg[node];
  float rd = dd > 0 ? rsqrtf((float)dd) : 0.f;
#pragma unroll
  for (int it = 0; it < 2; ++it) {
    int p = (lane >> 4) + it * 4;
    int s = lane & 15;
    if (s < c[p]) {
      int pos = off[p] + s;
      if (pos < CAP) {
        int sr = (int)ed16[(size_t)p * (N_NODES * PSLOT) + node * PSLOT + s];
        int ds = deg[sr];
        float w = (ds > 0 && dd > 0) ? -rsqrtf((float)ds) * rd : 0.f;
        edata[(node << 6) + pos] = pack_edge(w, sr);
      }
    }
  }
}

// ---- feature SpMV (R5-proven, unchanged) ----
__global__ __launch_bounds__(256) void k_spmv(const unsigned* __restrict__ edata,
                                              const int* __restrict__ cnt,
                                              const unsigned char* __restrict__ Q,
                                              const float* __restrict__ S,
                                              const _Float16* __restrict__ Z,
                                              _Float16* __restrict__ Y,
                                              unsigned char* __restrict__ Qo,
                                              float* __restrict__ So,
                                              float alpha, int hasZ, int writeY) {
  int wave = threadIdx.x >> 6, lane = threadIdx.x & 63;
  int q = lane >> 4, l16 = lane & 15;
  int node = blockIdx.x * 16 + wave * 4 + q;
  if (node >= N_NODES) return;
  int n_e = cnt[node]; if (n_e > CAP) n_e = CAP;
  int base = node << 6;

  float acc[8];
#pragma unroll
  for (int f = 0; f < 8; ++f) acc[f] = 0.f;
  float wsum = 0.f;

  unsigned e0 = (0 < n_e) ? edata[base + 0] : 0u;
  unsigned e1 = (1 < n_e) ? edata[base + 1] : 0u;
  unsigned e2 = (2 < n_e) ? edata[base + 2] : 0u;
  unsigned e3 = (3 < n_e) ? edata[base + 3] : 0u;
  unsigned e4 = (4 < n_e) ? edata[base + 4] : 0u;
  unsigned e5 = (5 < n_e) ? edata[base + 5] : 0u;
  unsigned e6 = (6 < n_e) ? edata[base + 6] : 0u;
  unsigned e7 = (7 < n_e) ? edata[base + 7] : 0u;
  uint2 r0 = ((const uint2*)(Q + (size_t)edge_src(e0) * FEAT))[l16];
  uint2 r1 = ((const uint2*)(Q + (size_t)edge_src(e1) * FEAT))[l16];
  uint2 r2 = ((const uint2*)(Q + (size_t)edge_src(e2) * FEAT))[l16];
  uint2 r3 = ((const uint2*)(Q + (size_t)edge_src(e3) * FEAT))[l16];
  float s0 = S[edge_src(e0)], s1 = S[edge_src(e1)], s2 = S[edge_src(e2)], s3 = S[edge_src(e3)];

  for (int j = 0; j < n_e; j += 4) {
    float ws0 = edge_w(e0) * s0, ws1 = edge_w(e1) * s1;
    float ws2 = edge_w(e2) * s2, ws3 = edge_w(e3) * s3;
    uint2 c0 = r0, c1 = r1, c2 = r2, c3 = r3;
    e0 = e4; e1 = e5; e2 = e6; e3 = e7;
    e4 = (j + 8 < n_e) ? edata[base + j + 8] : 0u;
    e5 = (j + 9 < n_e) ? edata[base + j + 9] : 0u;
    e6 = (j + 10 < n_e) ? edata[base + j + 10] : 0u;
    e7 = (j + 11 < n_e) ? edata[base + j + 11] : 0u;
    r0 = ((const uint2*)(Q + (size_t)edge_src(e0) * FEAT))[l16];
    r1 = ((const uint2*)(Q + (size_t)edge_src(e1) * FEAT))[l16];
    r2 = ((const uint2*)(Q + (size_t)edge_src(e2) * FEAT))[l16];
    r3 = ((const uint2*)(Q + (size_t)edge_src(e3) * FEAT))[l16];
    s0 = S[edge_src(e0)]; s1 = S[edge_src(e1)]; s2 = S[edge_src(e2)]; s3 = S[edge_src(e3)];
#define DEC8(c, w)                                                        \
    acc[0] = fmaf(w, (float)(c.x & 0xFFu), acc[0]);                       \
    acc[1] = fmaf(w, (float)((c.x >> 8) & 0xFFu), acc[1]);                \
    acc[2] = fmaf(w, (float)((c.x >> 16) & 0xFFu), acc[2]);               \
    acc[3] = fmaf(w, (float)(c.x >> 24), acc[3]);                         \
    acc[4] = fmaf(w, (float)(c.y & 0xFFu), acc[4]);                       \
    acc[5] = fmaf(w, (float)((c.y >> 8) & 0xFFu), acc[5]);                \
    acc[6] = fmaf(w, (float)((c.y >> 16) & 0xFFu), acc[6]);               \
    acc[7] = fmaf(w, (float)(c.y >> 24), acc[7]);
    DEC8(c0, ws0) DEC8(c1, ws1) DEC8(c2, ws2) DEC8(c3, ws3)
#undef DEC8
    wsum += (ws0 + ws1) + (ws2 + ws3);
  }
  float rx[8];
  float b128 = 128.f * wsum;
  if (hasZ) {
    half8 z = ((const half8*)(Z + (size_t)node * FEAT))[l16];
#pragma unroll
    for (int f = 0; f < 8; ++f) rx[f] = fmaf(alpha, acc[f] - b128, -(float)z[f]);
  } else {
#pragma unroll
    for (int f = 0; f < 8; ++f) rx[f] = alpha * (acc[f] - b128);
  }
  if (writeY) {
    half8 res;
#pragma unroll
    for (int f = 0; f < 8; ++f) res[f] = (_Float16)rx[f];
    ((half8*)(Y + (size_t)node * FEAT))[l16] = res;
  }
  float mx = 0.f;
#pragma unroll
  for (int f = 0; f < 8; ++f) mx = fmaxf(mx, fabsf(rx[f]));
#pragma unroll
  for (int o = 1; o < 16; o <<= 1) mx = fmaxf(mx, __shfl_xor(mx, o));
  float inv = mx > 0.f ? 127.f / mx : 0.f;
  int qb[8];
#pragma unroll
  for (int f = 0; f < 8; ++f) qb[f] = (int)rintf(rx[f] * inv) + 128;
  uint2 p;
  p.x = (unsigned)qb[0] | ((unsigned)qb[1] << 8) | ((unsigned)qb[2] << 16) | ((unsigned)qb[3] << 24);
  p.y = (unsigned)qb[4] | ((unsigned)qb[5] << 8) | ((unsigned)qb[6] << 16) | ((unsigned)qb[7] << 24);
  ((uint2*)(Qo + (size_t)node * FEAT))[l16] = p;
  if (l16 == 0) So[node] = mx > 0.f ? mx / 127.f : 0.f;
}

// ---- scalar SpMV (Clenshaw step) — R5-proven separate-launch version ----
__global__ __launch_bounds__(256) void k_smv(const unsigned* __restrict__ edata,
                                             const int* __restrict__ cnt,
                                             const float* __restrict__ h,
                                             const float* __restrict__ b,
                                             const float* __restrict__ bprev,
                                             float cL, float* __restrict__ y,
                                             int is_out, void* __restrict__ outp,
                                             const int* __restrict__ flag,
                                             const float* __restrict__ cptr) {
  int wave = threadIdx.x >> 6, lane = threadIdx.x & 63;
  int q = lane >> 4, l16 = lane & 15;
  int node = blockIdx.x * 16 + wave * 4 + q;
  if (node >= N_NODES) return;
  int n_e = cnt[node]; if (n_e > CAP) n_e = CAP;
  int base = node << 6;
  float s = 0.f;
  for (int j = l16; j < n_e; j += 16) {
    unsigned e = edata[base + j];
    s = fmaf(edge_w(e), b[edge_src(e)], s);
  }
#pragma unroll
  for (int o = 1; o < 16; o <<= 1) s += __shfl_xor(s, o);
  if (l16 == 0) {
    float r = fmaf(cL, s, h[node]) - (bprev ? bprev[node] : 0.f);
    if (!is_out) {
      y[node] = r;
    } else {
      r += cptr[0];
      if (flag[0]) ((float*)outp)[node] = r;
      else ((unsigned short*)outp)[node] = f2bf(r);
    }
  }
}

// ---- fused layer GEMM (R5-proven, unchanged) ----
__global__ __launch_bounds__(256) void k_gemm(const unsigned char* __restrict__ qa0, const unsigned char* __restrict__ qa1,
                                              const unsigned char* __restrict__ qa2, const unsigned char* __restrict__ qa3,
                                              const unsigned char* __restrict__ qa4,
                                              const float* __restrict__ sa0, const float* __restrict__ sa1,
                                              const float* __restrict__ sa2, const float* __restrict__ sa3,
                                              const float* __restrict__ sa4,
                                              const _Float16* __restrict__ wt,  // [5][128(n)][128(k)] fp16
                                              const float* __restrict__ bias,
                                              _Float16* __restrict__ dst, int mode,
                                              const float* __restrict__ v0,   // 5x128
                                              float* __restrict__ hout,       // 5xN
                                              unsigned char* __restrict__ q8out,
                                              float* __restrict__ scout) {
  __shared__ _Float16 lb[128 * 136];
  const unsigned char* qp[5] = {qa0, qa1, qa2, qa3, qa4};
  const float* sp[5] = {sa0, sa1, sa2, sa3, sa4};
  int tid = threadIdx.x, wave = tid >> 6, lane = tid & 63;
  int quad = lane >> 4, l16 = lane & 15;
  int m0 = blockIdx.x * 128;
  floatx4 acc[2][8];
#pragma unroll
  for (int s = 0; s < 2; ++s)
#pragma unroll
    for (int j = 0; j < 8; ++j) acc[s][j] = (floatx4){0.f, 0.f, 0.f, 0.f};
  int arow[2];
  bool aval[2];
#pragma unroll
  for (int s = 0; s < 2; ++s) {
    arow[s] = m0 + wave * 32 + s * 16 + l16;
    aval[s] = arow[s] < N_NODES;
  }

#pragma unroll
  for (int k = 0; k < 5; ++k) {
    __syncthreads();
    {
      int n = tid >> 1, half = tid & 1;
      const uint4* spw = (const uint4*)(wt + k * 16384 + n * 128 + half * 64);
      uint4* dq = (uint4*)(lb + n * 136 + half * 64);
#pragma unroll
      for (int i = 0; i < 8; ++i) dq[i] = spw[i];
    }
    __syncthreads();
    const unsigned char* Aq = qp[k];
    float sk[2];
#pragma unroll
    for (int s = 0; s < 2; ++s) sk[s] = aval[s] ? sp[k][arow[s]] : 0.f;
#pragma unroll
    for (int ki = 0; ki < 4; ++ki) {
      half8 af[2];
#pragma unroll
      for (int s = 0; s < 2; ++s) {
        uint2 qv = aval[s]
          ? *((const uint2*)(Aq + (size_t)arow[s] * FEAT + ki * 32 + quad * 8))
          : make_uint2(0x80808080u, 0x80808080u);
        af[s] = deq8(qv, sk[s]);
      }
#pragma unroll
      for (int j = 0; j < 8; ++j) {
        half8 bf = *((const half8*)(lb + (j * 16 + l16) * 136 + ki * 32 + quad * 8));
        acc[0][j] = __builtin_amdgcn_mfma_f32_16x16x32_f16(af[0], bf, acc[0][j], 0, 0, 0);
        acc[1][j] = __builtin_amdgcn_mfma_f32_16x16x32_f16(af[1], bf, acc[1][j], 0, 0, 0);
      }
    }
  }
#pragma unroll
  for (int s = 0; s < 2; ++s) {
    int rbase = m0 + wave * 32 + s * 16 + quad * 4;
    if (mode == 0) {
      float mx[4] = {0.f, 0.f, 0.f, 0.f};
#pragma unroll
      for (int j = 0; j < 8; ++j) {
        int col = j * 16 + l16;
        float b = bias[col];
#pragma unroll
        for (int r = 0; r < 4; ++r) {
          int m = rbase + r;
          float v = fmaxf(acc[s][j][r] + b, 0.f);
          if (m < N_NODES) dst[(size_t)m * FEAT + col] = (_Float16)v;
          mx[r] = fmaxf(mx[r], v);
        }
      }
#pragma unroll
      for (int o = 1; o < 16; o <<= 1) {
#pragma unroll
        for (int r = 0; r < 4; ++r) mx[r] = fmaxf(mx[r], __shfl_xor(mx[r], o));
      }
      float inv[4];
#pragma unroll
      for (int r = 0; r < 4; ++r) inv[r] = mx[r] > 0.f ? 127.f / mx[r] : 0.f;
      if (l16 == 0) {
#pragma unroll
        for (int r = 0; r < 4; ++r) {
          int m = rbase + r;
          if (m < N_NODES) scout[m] = mx[r] > 0.f ? mx[r] / 127.f : 0.f;
        }
      }
#pragma unroll
      for (int j = 0; j < 8; ++j) {
        int col = j * 16 + l16;
        float b = bias[col];
#pragma unroll
        for (int r = 0; r < 4; ++r) {
          int m = rbase + r;
          if (m < N_NODES) {
            float v = fmaxf(acc[s][j][r] + b, 0.f);
            int qv = (int)rintf(v * inv[r]) + 128;
            q8out[(size_t)m * FEAT + col] = (unsigned char)qv;
          }
        }
      }
    } else {
      float p[5][4];
#pragma unroll
      for (int k = 0; k < 5; ++k)
#pragma unroll
        for (int r = 0; r < 4; ++r) p[k][r] = 0.f;
#pragma unroll
      for (int j = 0; j < 8; ++j) {
        int col = j * 16 + l16;
        float b = bias[col];
        float vv[5];
#pragma unroll
        for (int k = 0; k < 5; ++k) vv[k] = v0[k * 128 + col];
#pragma unroll
        for (int r = 0; r < 4; ++r) {
          float val = fmaxf(acc[s][j][r] + b, 0.f);
#pragma unroll
          for (int k = 0; k < 5; ++k) p[k][r] = fmaf(val, vv[k], p[k][r]);
        }
      }
#pragma unroll
      for (int o = 1; o < 16; o <<= 1) {
#pragma unroll
        for (int k = 0; k < 5; ++k)
#pragma unroll
          for (int r = 0; r < 4; ++r) p[k][r] += __shfl_xor(p[k][r], o);
      }
      if (l16 == 0) {
#pragma unroll
        for (int r = 0; r < 4; ++r) {
          int m = rbase + r;
          if (m < N_NODES) {
#pragma unroll
            for (int k = 0; k < 5; ++k) hout[k * N_NODES + m] = p[k][r];
          }
        }
      }
    }
  }
}

extern "C" void kernel_launch(void* const* d_in, const int* in_sizes, int n_in,
                              void* d_out, int out_size, void* d_ws, size_t ws_size,
                              hipStream_t stream) {
  const void* x  = d_in[0];
  const int* ei  = (const int*)d_in[1];
  const void* w0 = d_in[2];
  const void* b0 = d_in[3];
  const void* w1 = d_in[4];
  const void* b1 = d_in[5];
  const void* w2 = d_in[6];
  const void* b2 = d_in[7];
  const void* wl = d_in[8];
  const void* bl = d_in[9];
  const int* src = ei;
  const int* dst = ei + N_EDGES;

  char* ws = (char*)d_ws;
  size_t off = 0;
  auto alloc = [&](size_t bytes) -> char* {
    char* p = ws + off;
    off += (bytes + 255) & ~(size_t)255;
    return p;
  };
  _Float16* T[3];
  for (int i = 0; i < 3; ++i) T[i] = (_Float16*)alloc(sizeof(_Float16) * N_NODES * FEAT);  // fp16 masters (Z-sources only)
  unsigned char* Q[5];
  for (int i = 0; i < 5; ++i) Q[i] = (unsigned char*)alloc((size_t)N_NODES * FEAT);        // int8 shadows
  float* S[5];
  for (int i = 0; i < 5; ++i) S[i] = (float*)alloc(sizeof(float) * N_NODES);               // row scales
  unsigned* edata = (unsigned*)alloc(sizeof(unsigned) * N_NODES * CAP);                    // 12.8 MB packed
  unsigned short* edata16 = (unsigned short*)alloc(sizeof(unsigned short) * 8 * N_NODES * PSLOT); // 12.8 MB partitioned
  int* cnt8 = (int*)alloc(sizeof(int) * N_NODES * 9);  // cnt8[8][N] + deg[N] (zeroed by pre1)
  int* deg = cnt8 + 8 * N_NODES;
  int* cnt = (int*)alloc(sizeof(int) * N_NODES);       // written by wpack
  _Float16* wt = (_Float16*)alloc(sizeof(_Float16) * 163840);
  float* pf = (float*)alloc(sizeof(float) * 1536);
  float* hbuf = (float*)alloc(sizeof(float) * 5 * N_NODES);  // h_k = relu(H1).v_k
  float* bbuf = (float*)alloc(sizeof(float) * 3 * N_NODES);  // Clenshaw b3,b2,b1
  int* flag = (int*)alloc(sizeof(int));

  k_pre1<<<64, 256, 0, stream>>>((const unsigned short*)x, b0, b1, b2, wl, bl, pf, flag, cnt8);
  k_pre2<<<B_TOT, 256, 0, stream>>>(x, w0, w1, w2, src, dst, T[0], Q[0], S[0], wt,
                                    deg, cnt8, edata16, pf, flag);
  k_wpack<<<(N_NODES * 64 + 255) / 256, 256, 0, stream>>>(edata16, cnt8, deg, cnt, edata);

  int nblk_spmv = (N_NODES + 15) / 16;
  int nblk_gemm = (N_NODES + 127) / 128;
  const float* v = pf + 520;       // v_k, 5x128
  const float* cc = pf + 1160;     // b2.Wl + bl

  // layers 0,1: T-chain via int8-shadow gathers; fp16 masters only for Z-operands.
  for (int l = 0; l < 2; ++l) {
    k_spmv<<<nblk_spmv, 256, 0, stream>>>(edata, cnt, Q[0], S[0], nullptr, T[1], Q[1], S[1], 1.f, 0, 1);
    k_spmv<<<nblk_spmv, 256, 0, stream>>>(edata, cnt, Q[1], S[1], T[0], T[2], Q[2], S[2], 2.f, 1, 1);
    k_spmv<<<nblk_spmv, 256, 0, stream>>>(edata, cnt, Q[2], S[2], T[1], nullptr, Q[3], S[3], 2.f, 1, 0);
    k_spmv<<<nblk_spmv, 256, 0, stream>>>(edata, cnt, Q[3], S[3], T[2], nullptr, Q[4], S[4], 2.f, 1, 0);
    k_gemm<<<nblk_gemm, 256, 0, stream>>>(Q[0], Q[1], Q[2], Q[3], Q[4],
                                          S[0], S[1], S[2], S[3], S[4],
                                          wt + l * 5 * 16384, pf + l * 128, T[0],
                                          l, v, hbuf, Q[0], S[0]);
  }
  // layer 2 via Clenshaw on scalar fields (fp32) — separate launches (R6 proved
  // cooperative grid.sync poisons the L2-resident gather working set)
  float* h0 = hbuf;
  float* h1 = hbuf + N_NODES;
  float* h2 = hbuf + 2 * N_NODES;
  float* h3 = hbuf + 3 * N_NODES;
  float* h4 = hbuf + 4 * N_NODES;
  float* b3 = bbuf;
  float* b2c = bbuf + N_NODES;
  float* b1c = bbuf + 2 * N_NODES;
  k_smv<<<nblk_spmv, 256, 0, stream>>>(edata, cnt, h3, h4, nullptr, 2.f, b3, 0, nullptr, flag, nullptr);
  k_smv<<<nblk_spmv, 256, 0, stream>>>(edata, cnt, h2, b3, h4, 2.f, b2c, 0, nullptr, flag, nullptr);
  k_smv<<<nblk_spmv, 256, 0, stream>>>(edata, cnt, h1, b2c, b3, 2.f, b1c, 0, nullptr, flag, nullptr);
  k_smv<<<nblk_spmv, 256, 0, stream>>>(edata, cnt, h0, b1c, b2c, 1.f, nullptr, 1, d_out, flag, cc);
}